// Round 7
// baseline (148.547 us; speedup 1.0000x reference)
//
#include <hip/hip_runtime.h>
#include <hip/hip_bf16.h>

#define N_NODES 100000
#define N_EDGES 1280000
#define D 64
#define NB ((N_NODES + 255) / 256)      // 391 (legacy scan blocks, tier-2)
#define NBKT 391                         // buckets of 256 nodes (tier-1)
#define BKT_SHIFT 8
#define BKT_NODES 256
#define COL_PAD 4096                     // col_lds size (pow2 for cheap masking)
#define SEG_E 4096                       // edges per bin segment
#define NSEG 313                         // ceil(E / SEG_E)
#define PRE_BLOCKS 782                   // ceil(6250 groups / 8 per block)

using short8 = __attribute__((ext_vector_type(8))) short;
using f32x4  = __attribute__((ext_vector_type(4))) float;

__device__ __forceinline__ unsigned short f2bf(float f) {
    unsigned int u = __float_as_uint(f);
    unsigned int r = (u + 0x7FFFu + ((u >> 16) & 1u)) >> 16;   // RNE
    return (unsigned short)r;
}

__device__ __forceinline__ float bf2f(unsigned short u) {
    union { unsigned int i; float f; } v;
    v.i = ((unsigned int)u) << 16;
    return v.f;
}

// Round-7: segment layout. Bin block i owns pairs[i*4096..] (coalesced uint4
// stores of its LDS-bucket-sorted edges) + publishes off_tab[bucket][seg].
// No global bcnt -> no zero kernel -> 2 dispatches total. Round-5 lesson:
// latency-bound pipeline lives on waves-in-flight; keep separate dispatches
// for phases, shave boundaries instead.

// ==================== fused bin + precompute (dispatch 1) ===================
__launch_bounds__(512)
__global__ void bin_pre_kernel(const int* __restrict__ row,
                               const int* __restrict__ col,
                               int* __restrict__ off_tab,      // [NBKT+1][NSEG]
                               unsigned int* __restrict__ pairs,
                               const float* __restrict__ x,
                               const float* __restrict__ W,
                               const float* __restrict__ Wr,
                               const float* __restrict__ bias,
                               unsigned int* __restrict__ y_packed,
                               float* __restrict__ out) {
    __shared__ __align__(16) char smem[22784];
    int tid = threadIdx.x;
    int blk = blockIdx.x;

    if (blk < NSEG) {
        // ---------------- bin path ----------------
        unsigned int* sorted = (unsigned int*)smem;        // 4096 * 4B
        int* cnt   = (int*)(smem + 16384);                 // NBKT each
        int* lexcl = cnt + NBKT;
        int* lcur  = lexcl + NBKT;
        int* wsum  = lcur + NBKT;                          // 8
        int* wexcl = wsum + 8;                             // 8

        int blk_edges = N_EDGES - blk * SEG_E;
        if (blk_edges > SEG_E) blk_edges = SEG_E;

        for (int i = tid; i < NBKT; i += 512) cnt[i] = 0;
        __syncthreads();

        int rr[8], cc[8];
#pragma unroll
        for (int i = 0; i < 8; ++i) {
            int idx = i * 512 + tid;
            if (idx < blk_edges) {
                int e = blk * SEG_E + idx;                 // coalesced per i
                rr[i] = row[e];
                cc[i] = col[e];
                atomicAdd(&cnt[rr[i] >> BKT_SHIFT], 1);
            } else {
                rr[i] = -1;
            }
        }
        __syncthreads();

        // shuffle scan over NBKT counts (8 waves + wave-0 combine)
        int lane = tid & 63, wv = tid >> 6;
        int v = (tid < NBKT) ? cnt[tid] : 0;
        int incl = v;
#pragma unroll
        for (int d = 1; d < 64; d <<= 1) {
            int u = __shfl_up(incl, d, 64);
            if (lane >= d) incl += u;
        }
        if (lane == 63) wsum[wv] = incl;
        __syncthreads();
        if (tid < 8) {
            int w = wsum[tid];
            int p = w;
#pragma unroll
            for (int d = 1; d < 8; d <<= 1) {
                int u = __shfl_up(p, d, 64);
                if (tid >= d) p += u;
            }
            wexcl[tid] = p - w;
        }
        __syncthreads();
        if (tid < NBKT) {
            int excl = incl - v + wexcl[wv];
            lexcl[tid] = excl;
            lcur[tid]  = excl;
            off_tab[tid * NSEG + blk] = excl;              // publish offsets
        }
        if (tid == NBKT) off_tab[NBKT * NSEG + blk] = blk_edges;
        __syncthreads();

        // scatter into LDS bucket-sorted order (1 LDS atomic per edge)
#pragma unroll
        for (int i = 0; i < 8; ++i) {
            if (rr[i] >= 0) {
                int b = rr[i] >> BKT_SHIFT;
                int slot = atomicAdd(&lcur[b], 1);
                sorted[slot] = ((unsigned int)(rr[i] & (BKT_NODES - 1)) << 17)
                             | (unsigned int)cc[i];
            }
        }
        __syncthreads();

        // perfectly coalesced copy-out: whole segment, uint4
        uint4* dst = (uint4*)(pairs + (size_t)blk * SEG_E);
        const uint4* src = (const uint4*)sorted;
#pragma unroll
        for (int i = 0; i < 2; ++i)
            dst[i * 512 + tid] = src[i * 512 + tid];
    } else {
        // ---------------- precompute path ----------------
        // y = x@W (bf16, pair-packed dword stores); out = x@Wr + bias.
        // Layouts (m89/m120-verified): A[m=lane&15][k=(lane>>4)*8+j];
        // B[k=(lane>>4)*8+j][n=lane&15]; C/D col=lane&15, row=(lane>>4)*4+reg.
        unsigned short* Wl = (unsigned short*)smem;   // [mat][t][h][lane][j]

        for (int idx = tid; idx < 8192; idx += 512) {
            int j    = idx & 7;
            int lane = (idx >> 3) & 63;
            int h    = (idx >> 9) & 1;
            int t    = (idx >> 10) & 3;
            int mat  = idx >> 12;
            int k = h * 32 + ((lane >> 4) << 3) + j;
            int n = t * 16 + (lane & 15);
            const float* src = mat ? Wr : W;
            Wl[idx] = f2bf(src[k * D + n]);
        }
        __syncthreads();

        int wv = tid >> 6;
        int lane = tid & 63;
        int g = (blk - NSEG) * 8 + wv;               // 16-node group id
        if (g >= N_NODES / 16) return;

        int quad = lane >> 4;
        int n16 = lane & 15;
        int m_node = g * 16 + n16;

        short8 A[2];
#pragma unroll
        for (int h = 0; h < 2; ++h) {
            const float* xr = x + (size_t)m_node * D + h * 32 + quad * 8;
            float4 xa = *(const float4*)xr;
            float4 xb = *(const float4*)(xr + 4);
            short8 a;
            a[0] = (short)f2bf(xa.x); a[1] = (short)f2bf(xa.y);
            a[2] = (short)f2bf(xa.z); a[3] = (short)f2bf(xa.w);
            a[4] = (short)f2bf(xb.x); a[5] = (short)f2bf(xb.y);
            a[6] = (short)f2bf(xb.z); a[7] = (short)f2bf(xb.w);
            A[h] = a;
        }

        int row0 = g * 16 + quad * 4;

#pragma unroll
        for (int t = 0; t < 4; ++t) {
            short8 By0 = *(const short8*)&Wl[(((0 * 4 + t) * 2 + 0) * 64 + lane) * 8];
            short8 By1 = *(const short8*)&Wl[(((0 * 4 + t) * 2 + 1) * 64 + lane) * 8];
            short8 Bz0 = *(const short8*)&Wl[(((1 * 4 + t) * 2 + 0) * 64 + lane) * 8];
            short8 Bz1 = *(const short8*)&Wl[(((1 * 4 + t) * 2 + 1) * 64 + lane) * 8];

            f32x4 accY = {0.f, 0.f, 0.f, 0.f};
            accY = __builtin_amdgcn_mfma_f32_16x16x32_bf16(A[0], By0, accY, 0, 0, 0);
            accY = __builtin_amdgcn_mfma_f32_16x16x32_bf16(A[1], By1, accY, 0, 0, 0);
            f32x4 accZ = {0.f, 0.f, 0.f, 0.f};
            accZ = __builtin_amdgcn_mfma_f32_16x16x32_bf16(A[0], Bz0, accZ, 0, 0, 0);
            accZ = __builtin_amdgcn_mfma_f32_16x16x32_bf16(A[1], Bz1, accZ, 0, 0, 0);

            float bv = bias[t * 16 + n16];
#pragma unroll
            for (int r = 0; r < 4; ++r) {
                out[(size_t)(row0 + r) * D + t * 16 + n16] = accZ[r] + bv;
                unsigned int me = f2bf(accY[r]);
                unsigned int nb = (unsigned int)__shfl_xor((int)me, 1, 64) & 0xFFFFu;
                if ((lane & 1) == 0)
                    y_packed[((size_t)(row0 + r) * D + t * 16 + n16) >> 1] = me | (nb << 16);
            }
        }
    }
}

// ==================== per-bucket CSR build + gather (dispatch 2) ============
// Block b = bucket b. Reads its 313 segment-runs (L2-hot) twice: count pass,
// then scatter into col_lds; then the round-4-proven register gather.
__launch_bounds__(1024, 8)
__global__ void csr_gather_kernel(const unsigned short* __restrict__ yu,
                                  const unsigned int* __restrict__ pairs,
                                  const int* __restrict__ off_tab,
                                  float* __restrict__ out) {
    __shared__ int col_lds[COL_PAD];      // 16 KB
    __shared__ int deg_s[BKT_NODES];
    __shared__ int start_s[BKT_NODES];
    __shared__ int lcur[BKT_NODES];
    __shared__ int cnt_s[BKT_NODES];
    __shared__ int wsum[4];
    __shared__ int soff[NSEG];
    __shared__ int slen[NSEG];

    int b = blockIdx.x;
    int tid = threadIdx.x;

    if (tid < NSEG) {
        int s0 = off_tab[b * NSEG + tid];
        soff[tid] = s0;
        slen[tid] = off_tab[(b + 1) * NSEG + tid] - s0;
    }
    if (tid < BKT_NODES) cnt_s[tid] = 0;
    __syncthreads();

    int grp = tid >> 4, l16 = tid & 15;   // 64 groups of 16 lanes

    // ---- count pass ----
    for (int seg = grp; seg < NSEG; seg += 64) {
        const unsigned int* p = pairs + (size_t)seg * SEG_E + soff[seg];
        int len = slen[seg];
        for (int k = l16; k < len; k += 16)
            atomicAdd(&cnt_s[p[k] >> 17], 1);
    }
    __syncthreads();

    // ---- 2-barrier shuffle scan over 256 counts (waves 0..3) ----
    if (tid < BKT_NODES) {
        int v = cnt_s[tid];
        int incl = v;
        for (int d = 1; d < 64; d <<= 1) {
            int t = __shfl_up(incl, d, 64);
            if ((tid & 63) >= d) incl += t;
        }
        if ((tid & 63) == 63) wsum[tid >> 6] = incl;
        deg_s[tid] = v;
        cnt_s[tid] = incl;
    }
    __syncthreads();
    if (tid < BKT_NODES) {
        int w = tid >> 6;
        int pre = 0;
        if (w > 0) pre += wsum[0];
        if (w > 1) pre += wsum[1];
        if (w > 2) pre += wsum[2];
        int excl = cnt_s[tid] + pre - deg_s[tid];
        start_s[tid] = excl;
        lcur[tid] = excl;
    }
    __syncthreads();

    // ---- scatter pass ----
    for (int seg = grp; seg < NSEG; seg += 64) {
        const unsigned int* p = pairs + (size_t)seg * SEG_E + soff[seg];
        int len = slen[seg];
        for (int k = l16; k < len; k += 16) {
            unsigned int e = p[k];
            int r = (int)(e >> 17);
            int c = (int)(e & 0x1FFFFu);
            col_lds[atomicAdd(&lcur[r], 1) & (COL_PAD - 1)] = c < N_NODES ? c : 0;
        }
    }
    __syncthreads();

    // ---- proven 4-node/wave register gather (round-4 form) ----
    int wv = tid >> 6;                    // 0..15
    int lane = tid & 63;
    int s = lane >> 4;
    int q = lane & 15;

#pragma unroll 1
    for (int pk = 0; pk < 4; ++pk) {
        int n0 = wv * 16 + pk * 4;        // local node base, 0..252
        int nvx = deg_s[n0 + 0], nvy = deg_s[n0 + 1],
            nvz = deg_s[n0 + 2], nvw = deg_s[n0 + 3];
        int st0 = start_s[n0 + 0], st1 = start_s[n0 + 1],
            st2 = start_s[n0 + 2], st3 = start_s[n0 + 3];

        float4 a0 = make_float4(0.f, 0.f, 0.f, 0.f);
        float4 a1 = a0, a2 = a0, a3 = a0;

        {
            int mm = nvx > nvy ? nvx : nvy;
            for (int j = 0; j < mm; j += 4) {
                int jj = j + s;
                int c0 = col_lds[(st0 + jj) & (COL_PAD - 1)];
                int c1 = col_lds[(st1 + jj) & (COL_PAD - 1)];
                c0 = (jj < nvx) ? c0 : 0;
                c1 = (jj < nvy) ? c1 : 0;
                ushort4 u0 = *(const ushort4*)&yu[(size_t)c0 * D + q * 4];
                ushort4 u1 = *(const ushort4*)&yu[(size_t)c1 * D + q * 4];
                if (jj < nvx) {
                    a0.x += bf2f(u0.x); a0.y += bf2f(u0.y);
                    a0.z += bf2f(u0.z); a0.w += bf2f(u0.w);
                }
                if (jj < nvy) {
                    a1.x += bf2f(u1.x); a1.y += bf2f(u1.y);
                    a1.z += bf2f(u1.z); a1.w += bf2f(u1.w);
                }
            }
        }
        {
            int mm = nvz > nvw ? nvz : nvw;
            for (int j = 0; j < mm; j += 4) {
                int jj = j + s;
                int c2 = col_lds[(st2 + jj) & (COL_PAD - 1)];
                int c3 = col_lds[(st3 + jj) & (COL_PAD - 1)];
                c2 = (jj < nvz) ? c2 : 0;
                c3 = (jj < nvw) ? c3 : 0;
                ushort4 u2 = *(const ushort4*)&yu[(size_t)c2 * D + q * 4];
                ushort4 u3 = *(const ushort4*)&yu[(size_t)c3 * D + q * 4];
                if (jj < nvz) {
                    a2.x += bf2f(u2.x); a2.y += bf2f(u2.y);
                    a2.z += bf2f(u2.z); a2.w += bf2f(u2.w);
                }
                if (jj < nvw) {
                    a3.x += bf2f(u3.x); a3.y += bf2f(u3.y);
                    a3.z += bf2f(u3.z); a3.w += bf2f(u3.w);
                }
            }
        }

#define BFLY(a) \
    a.x += __shfl_xor(a.x, 16, 64); a.y += __shfl_xor(a.y, 16, 64); \
    a.z += __shfl_xor(a.z, 16, 64); a.w += __shfl_xor(a.w, 16, 64); \
    a.x += __shfl_xor(a.x, 32, 64); a.y += __shfl_xor(a.y, 32, 64); \
    a.z += __shfl_xor(a.z, 32, 64); a.w += __shfl_xor(a.w, 32, 64);
        BFLY(a0) BFLY(a1) BFLY(a2) BFLY(a3)
#undef BFLY

        float inv0 = 1.0f / (float)(nvx > 1 ? nvx : 1);
        float inv1 = 1.0f / (float)(nvy > 1 ? nvy : 1);
        float inv2 = 1.0f / (float)(nvz > 1 ? nvz : 1);
        float inv3 = 1.0f / (float)(nvw > 1 ? nvw : 1);

        float4 rr = (s == 0) ? a0 : (s == 1) ? a1 : (s == 2) ? a2 : a3;
        float invs = (s == 0) ? inv0 : (s == 1) ? inv1 : (s == 2) ? inv2 : inv3;
        int g = (b << BKT_SHIFT) + n0 + s;
        if (g < N_NODES) {
            size_t off = (size_t)g * D + q * 4;
            float4 z = *(const float4*)&out[off];
            z.x += rr.x * invs; z.y += rr.y * invs;
            z.z += rr.z * invs; z.w += rr.w * invs;
            *(float4*)&out[off] = z;
        }
    }
}

// ==================== tier-2: legacy CSR build + fused aggregate ============

__global__ void hist_kernel(const int4* __restrict__ row4, int* __restrict__ deg) {
    int t = blockIdx.x * blockDim.x + threadIdx.x;
    if (t < N_EDGES / 4) {
        int4 r = row4[t];
        atomicAdd(&deg[r.x], 1);
        atomicAdd(&deg[r.y], 1);
        atomicAdd(&deg[r.z], 1);
        atomicAdd(&deg[r.w], 1);
    }
}

__global__ void scan_block_kernel(const int* __restrict__ deg,
                                  int* __restrict__ cursor,
                                  int* __restrict__ bsum) {
    __shared__ int s[256];
    int tid = threadIdx.x;
    int gid = blockIdx.x * 256 + tid;
    int v = (gid < N_NODES) ? deg[gid] : 0;
    s[tid] = v;
    __syncthreads();
    for (int d = 1; d < 256; d <<= 1) {
        int t = (tid >= d) ? s[tid - d] : 0;
        __syncthreads();
        s[tid] += t;
        __syncthreads();
    }
    if (gid < N_NODES) cursor[gid] = s[tid] - v;
    if (tid == 255) bsum[blockIdx.x] = s[255];
}

__global__ void add_offsets_kernel(int* __restrict__ cursor,
                                   const int* __restrict__ bsum_raw) {
    __shared__ int red[256];
    int tid = threadIdx.x;
    int b = blockIdx.x;
    int sum = 0;
    for (int i = tid; i < b; i += 256) sum += bsum_raw[i];
    red[tid] = sum;
    __syncthreads();
    for (int off = 128; off > 0; off >>= 1) {
        if (tid < off) red[tid] += red[tid + off];
        __syncthreads();
    }
    int gid = b * 256 + tid;
    if (gid < N_NODES) cursor[gid] += red[0];
}

__global__ void scatter_build_kernel(const int4* __restrict__ row4,
                                     const int4* __restrict__ col4,
                                     int* __restrict__ cursor,
                                     int* __restrict__ col_sorted) {
    int t = blockIdx.x * blockDim.x + threadIdx.x;
    if (t < N_EDGES / 4) {
        int4 r = row4[t];
        int4 c = col4[t];
        col_sorted[atomicAdd(&cursor[r.x], 1)] = c.x;
        col_sorted[atomicAdd(&cursor[r.y], 1)] = c.y;
        col_sorted[atomicAdd(&cursor[r.z], 1)] = c.z;
        col_sorted[atomicAdd(&cursor[r.w], 1)] = c.w;
    }
}

__launch_bounds__(512, 8)
__global__ void aggregate_kernel(const float* __restrict__ x,
                                 const int* __restrict__ cursor_end,
                                 const int* __restrict__ deg,
                                 const int* __restrict__ col_sorted,
                                 const float* __restrict__ W,
                                 const float* __restrict__ Wr,
                                 const float* __restrict__ bias,
                                 float* __restrict__ out) {
    __shared__ float Ws[D * D];
    __shared__ float Wrs[D * D];
    __shared__ float agg_s[8][D];
    __shared__ float x_s[8][D];

    for (int i = threadIdx.x; i < D * D / 4; i += 512) {
        ((float4*)Ws)[i]  = ((const float4*)W)[i];
        ((float4*)Wrs)[i] = ((const float4*)Wr)[i];
    }
    __syncthreads();

    int wv = threadIdx.x >> 6;
    int lane = threadIdx.x & 63;
    int s = lane >> 4;
    int q = lane & 15;
    float bf = bias[lane];

    int node0 = (blockIdx.x * 8 + wv) * 4;

#pragma unroll 1
    for (int nn = 0; nn < 4; ++nn) {
        int r = node0 + nn;
        int n = deg[r];
        int start = cursor_end[r] - n;

        float4 acc = make_float4(0.f, 0.f, 0.f, 0.f);
        for (int base = 0; base < n; base += 64) {
            int m = n - base; if (m > 64) m = 64;
            int idx = 0;
            if (lane < m) idx = col_sorted[start + base + lane];
            for (int j = 0; j < m; j += 4) {
                int jj = j + s;
                int c = __shfl(idx, jj, 64);
                if (jj < m) {
                    float4 v = *(const float4*)&x[(size_t)c * D + q * 4];
                    acc.x += v.x; acc.y += v.y; acc.z += v.z; acc.w += v.w;
                }
            }
        }
        acc.x += __shfl_xor(acc.x, 16, 64);
        acc.y += __shfl_xor(acc.y, 16, 64);
        acc.z += __shfl_xor(acc.z, 16, 64);
        acc.w += __shfl_xor(acc.w, 16, 64);
        acc.x += __shfl_xor(acc.x, 32, 64);
        acc.y += __shfl_xor(acc.y, 32, 64);
        acc.z += __shfl_xor(acc.z, 32, 64);
        acc.w += __shfl_xor(acc.w, 32, 64);

        float inv = 1.0f / (float)(n > 1 ? n : 1);
        if (lane < 16) {
            float4 a = make_float4(acc.x * inv, acc.y * inv, acc.z * inv, acc.w * inv);
            *(float4*)&agg_s[wv][q * 4] = a;
            *(float4*)&x_s[wv][q * 4] = *(const float4*)&x[(size_t)r * D + q * 4];
        }
        __builtin_amdgcn_wave_barrier();

        int f = lane;
        float o = bf;
        const float4* av = (const float4*)agg_s[wv];
        const float4* xv = (const float4*)x_s[wv];
#pragma unroll
        for (int k4 = 0; k4 < 16; ++k4) {
            float4 a = av[k4];
            float4 xx = xv[k4];
            int k = k4 * 4;
            o += a.x * Ws[(k + 0) * D + f] + xx.x * Wrs[(k + 0) * D + f];
            o += a.y * Ws[(k + 1) * D + f] + xx.y * Wrs[(k + 1) * D + f];
            o += a.z * Ws[(k + 2) * D + f] + xx.z * Wrs[(k + 2) * D + f];
            o += a.w * Ws[(k + 3) * D + f] + xx.w * Wrs[(k + 3) * D + f];
        }
        out[(size_t)r * D + f] = o;
        __builtin_amdgcn_wave_barrier();
    }
}

// ==================== tier-3: atomic fallback (400 KB ws) ====================

__global__ void zero_kernel(float* __restrict__ summed, float* __restrict__ cnt) {
    int stride = gridDim.x * blockDim.x;
    int i = blockIdx.x * blockDim.x + threadIdx.x;
    const int total = N_NODES * D;
    for (int idx = i; idx < total; idx += stride) summed[idx] = 0.0f;
    for (int idx = i; idx < N_NODES; idx += stride) cnt[idx] = 0.0f;
}

__global__ void scatter_atomic_kernel(const float* __restrict__ x,
                                      const int* __restrict__ row,
                                      const int* __restrict__ col,
                                      float* __restrict__ summed,
                                      float* __restrict__ cnt) {
    long long gid = (long long)blockIdx.x * blockDim.x + threadIdx.x;
    const long long total = (long long)N_EDGES * D;
    if (gid >= total) return;
    int e = (int)(gid >> 6);
    int f = (int)(gid & 63);
    int r = row[e];
    int c = col[e];
    atomicAdd(&summed[r * D + f], x[c * D + f]);
    if (f == 0) atomicAdd(&cnt[r], 1.0f);
}

__global__ void finish_kernel(const float* __restrict__ x,
                              const float* __restrict__ W,
                              const float* __restrict__ Wr,
                              const float* __restrict__ bias,
                              const float* __restrict__ cnt,
                              float* __restrict__ out) {
    __shared__ float agg_s[4][D];
    __shared__ float x_s[4][D];
    int lrow = threadIdx.x >> 6;
    int f = threadIdx.x & 63;
    int r = blockIdx.x * 4 + lrow;

    float c = cnt[r];
    float inv = 1.0f / fmaxf(c, 1.0f);
    agg_s[lrow][f] = out[r * D + f] * inv;
    x_s[lrow][f] = x[r * D + f];
    __syncthreads();

    float acc = bias[f];
#pragma unroll 8
    for (int k = 0; k < D; ++k) {
        acc += agg_s[lrow][k] * W[k * D + f];
        acc += x_s[lrow][k] * Wr[k * D + f];
    }
    out[r * D + f] = acc;
}

// ==================== launch ====================

extern "C" void kernel_launch(void* const* d_in, const int* in_sizes, int n_in,
                              void* d_out, int out_size, void* d_ws, size_t ws_size,
                              hipStream_t stream) {
    const float* x    = (const float*)d_in[0];
    const int*   ei   = (const int*)d_in[1];   // [2, E]: row = ei, col = ei + E
    const float* W    = (const float*)d_in[2];
    const float* Wr   = (const float*)d_in[3];
    const float* bias = (const float*)d_in[4];
    float* out = (float*)d_out;

    const int* row = ei;
    const int* col = ei + N_EDGES;

    // tier-1 layout: off_tab(392*313*4 = 490,784) | pairs(313*4096*4 = 5,128,192)
    //              | y(12,800,000)  => total 18,418,976
    const size_t t1_off   = 0;
    const size_t t1_pairs = (size_t)(NBKT + 1) * NSEG * 4;         //   490,784
    const size_t t1_y     = t1_pairs + (size_t)NSEG * SEG_E * 4;   // 5,618,976
    const size_t t1_need  = t1_y + (size_t)N_NODES * D * 2;        // 18,418,976

    const size_t csr_bytes = (size_t)2 * N_NODES * 4 + 2048 + (size_t)N_EDGES * 4;

    if (ws_size >= t1_need) {
        char* ws = (char*)d_ws;
        int* off_tab = (int*)(ws + t1_off);
        unsigned int* pairs    = (unsigned int*)(ws + t1_pairs);
        unsigned int* y_packed = (unsigned int*)(ws + t1_y);

        bin_pre_kernel<<<NSEG + PRE_BLOCKS, 512, 0, stream>>>(
            row, col, off_tab, pairs, x, W, Wr, bias, y_packed, out);
        csr_gather_kernel<<<NBKT, 1024, 0, stream>>>(
            (const unsigned short*)y_packed, pairs, off_tab, out);
    } else if (ws_size >= csr_bytes) {
        char* ws = (char*)d_ws;
        int* deg        = (int*)(ws);
        int* cursor     = (int*)(ws + (size_t)1 * N_NODES * 4);
        int* bsum       = (int*)(ws + (size_t)2 * N_NODES * 4);
        int* col_sorted = (int*)(ws + (size_t)2 * N_NODES * 4 + 2048);

        hipMemsetAsync(deg, 0, (size_t)N_NODES * 4, stream);
        hist_kernel<<<(N_EDGES / 4 + 255) / 256, 256, 0, stream>>>((const int4*)row, deg);
        scan_block_kernel<<<NB, 256, 0, stream>>>(deg, cursor, bsum);
        add_offsets_kernel<<<NB, 256, 0, stream>>>(cursor, bsum);
        scatter_build_kernel<<<(N_EDGES / 4 + 255) / 256, 256, 0, stream>>>(
            (const int4*)row, (const int4*)col, cursor, col_sorted);
        aggregate_kernel<<<N_NODES / 32, 512, 0, stream>>>(x, cursor, deg, col_sorted, W, Wr, bias, out);
    } else {
        float* cnt = (float*)d_ws;   // N_NODES floats
        zero_kernel<<<4096, 256, 0, stream>>>(out, cnt);
        long long total = (long long)N_EDGES * D;
        int blocks = (int)((total + 255) / 256);
        scatter_atomic_kernel<<<blocks, 256, 0, stream>>>(x, row, col, out, cnt);
        finish_kernel<<<(N_NODES + 3) / 4, 256, 0, stream>>>(x, W, Wr, bias, cnt, out);
    }
}

// Round 8
// 141.716 us; speedup vs baseline: 1.0482x; 1.0482x over previous
//
#include <hip/hip_runtime.h>
#include <hip/hip_bf16.h>

#define N_NODES 100000
#define N_EDGES 1280000
#define D 64
#define NB ((N_NODES + 255) / 256)      // 391 (legacy scan blocks, tier-2)
#define NBKT 391                         // buckets of 256 nodes (tier-1)
#define BKT_SHIFT 8
#define BKT_NODES 256
#define CAP 3712                         // static bucket capacity (mean 3273, +7.7 sigma)
#define HBKT 782                         // half-bucket gather blocks
#define HALF_PAD 2048                    // col_lds per half-bucket (pow2 mask)
#define BIN_EPB 4096                     // edges per bin block
#define BIN_BLOCKS 313                   // ceil(E / BIN_EPB)
#define PRE_BLOCKS 782                   // ceil(6250 groups / 8 per block)

using short8 = __attribute__((ext_vector_type(8))) short;
using f32x4  = __attribute__((ext_vector_type(4))) float;

__device__ __forceinline__ unsigned short f2bf(float f) {
    unsigned int u = __float_as_uint(f);
    unsigned int r = (u + 0x7FFFu + ((u >> 16) & 1u)) >> 16;   // RNE
    return (unsigned short)r;
}

__device__ __forceinline__ float bf2f(unsigned short u) {
    union { unsigned int i; float f; } v;
    v.i = ((unsigned int)u) << 16;
    return v.f;
}

// Round-8: revert to proven round-4 pipeline (140.5us); single change = gather
// split into 782 half-bucket blocks. Round-7 counters showed gather occupancy
// 50.7% (391 blocks x 16 waves = 1.5 blocks/CU) -- grid-size-starved TLP for
// the L3-random y gather. 512-thread half-bucket blocks give ~3 blocks/CU.

__global__ void zero_bcnt_kernel(int* __restrict__ bcnt) {
    int t = threadIdx.x;
    if (t < NBKT) bcnt[t] = 0;
}

// ==================== fused bin + precompute (round-4 proven) ===============
__launch_bounds__(512)
__global__ void bin_pre_kernel(const int* __restrict__ row,
                               const int* __restrict__ col,
                               int* __restrict__ bucket_cnt,   // pre-zeroed
                               unsigned int* __restrict__ pairs,
                               const float* __restrict__ x,
                               const float* __restrict__ W,
                               const float* __restrict__ Wr,
                               const float* __restrict__ bias,
                               unsigned int* __restrict__ y_packed,
                               float* __restrict__ out) {
    __shared__ __align__(16) char smem[22784];
    int tid = threadIdx.x;

    if (blockIdx.x < BIN_BLOCKS) {
        // ---------------- bin path ----------------
        unsigned int* sorted = (unsigned int*)smem;        // 4096 * 4B
        int* cnt   = (int*)(smem + 16384);                 // NBKT each
        int* lexcl = cnt + NBKT;
        int* lcur  = lexcl + NBKT;
        int* gbase = lcur + NBKT;
        int* wsum  = gbase + NBKT;                         // 8
        int* wexcl = wsum + 8;                             // 8

        for (int i = tid; i < NBKT; i += 512) cnt[i] = 0;
        __syncthreads();

        int rr[8], cc[8];
#pragma unroll
        for (int i = 0; i < 8; ++i) {
            int e = blockIdx.x * BIN_EPB + i * 512 + tid;  // coalesced per i
            if (e < N_EDGES) {
                rr[i] = row[e];
                cc[i] = col[e];
                atomicAdd(&cnt[rr[i] >> BKT_SHIFT], 1);
            } else {
                rr[i] = -1;
            }
        }
        __syncthreads();

        // shuffle scan over NBKT counts (8 waves + wave-0 combine)
        int lane = tid & 63, wv = tid >> 6;
        int v = (tid < NBKT) ? cnt[tid] : 0;
        int incl = v;
#pragma unroll
        for (int d = 1; d < 64; d <<= 1) {
            int u = __shfl_up(incl, d, 64);
            if (lane >= d) incl += u;
        }
        if (lane == 63) wsum[wv] = incl;
        __syncthreads();
        if (tid < 8) {
            int w = wsum[tid];
            int p = w;
#pragma unroll
            for (int d = 1; d < 8; d <<= 1) {
                int u = __shfl_up(p, d, 64);
                if (tid >= d) p += u;
            }
            wexcl[tid] = p - w;
        }
        __syncthreads();
        if (tid < NBKT) {
            int excl = incl - v + wexcl[wv];
            lexcl[tid] = excl;
            lcur[tid]  = excl;
            if (v > 0) gbase[tid] = atomicAdd(&bucket_cnt[tid], v);
        }
        __syncthreads();

        // scatter into LDS-sorted order (1 LDS atomic per edge)
#pragma unroll
        for (int i = 0; i < 8; ++i) {
            if (rr[i] >= 0) {
                int b = rr[i] >> BKT_SHIFT;
                int slot = atomicAdd(&lcur[b], 1);
                sorted[slot] = ((unsigned int)(rr[i] & (BKT_NODES - 1)) << 17)
                             | (unsigned int)cc[i];
            }
        }
        __syncthreads();

        // coalesced copy-out: 16-lane group per bucket run
        int grp = tid >> 4, l16 = tid & 15;
        for (int bb = grp; bb < NBKT; bb += 32) {
            int len = cnt[bb];
            if (len == 0) continue;
            int src = lexcl[bb];
            int dst = gbase[bb];
            for (int k = l16; k < len; k += 16) {
                int gs = dst + k;
                if (gs < CAP)
                    pairs[(size_t)bb * CAP + gs] = sorted[src + k];
            }
        }
    } else {
        // ---------------- precompute path ----------------
        // y = x@W (bf16, pair-packed dword stores); out = x@Wr + bias.
        // Layouts (m89/m120-verified): A[m=lane&15][k=(lane>>4)*8+j];
        // B[k=(lane>>4)*8+j][n=lane&15]; C/D col=lane&15, row=(lane>>4)*4+reg.
        unsigned short* Wl = (unsigned short*)smem;   // [mat][t][h][lane][j]

        for (int idx = tid; idx < 8192; idx += 512) {
            int j    = idx & 7;
            int lane = (idx >> 3) & 63;
            int h    = (idx >> 9) & 1;
            int t    = (idx >> 10) & 3;
            int mat  = idx >> 12;
            int k = h * 32 + ((lane >> 4) << 3) + j;
            int n = t * 16 + (lane & 15);
            const float* src = mat ? Wr : W;
            Wl[idx] = f2bf(src[k * D + n]);
        }
        __syncthreads();

        int wv = tid >> 6;
        int lane = tid & 63;
        int g = (blockIdx.x - BIN_BLOCKS) * 8 + wv;   // 16-node group id
        if (g >= N_NODES / 16) return;

        int quad = lane >> 4;
        int n16 = lane & 15;
        int m_node = g * 16 + n16;

        short8 A[2];
#pragma unroll
        for (int h = 0; h < 2; ++h) {
            const float* xr = x + (size_t)m_node * D + h * 32 + quad * 8;
            float4 xa = *(const float4*)xr;
            float4 xb = *(const float4*)(xr + 4);
            short8 a;
            a[0] = (short)f2bf(xa.x); a[1] = (short)f2bf(xa.y);
            a[2] = (short)f2bf(xa.z); a[3] = (short)f2bf(xa.w);
            a[4] = (short)f2bf(xb.x); a[5] = (short)f2bf(xb.y);
            a[6] = (short)f2bf(xb.z); a[7] = (short)f2bf(xb.w);
            A[h] = a;
        }

        int row0 = g * 16 + quad * 4;

#pragma unroll
        for (int t = 0; t < 4; ++t) {
            short8 By0 = *(const short8*)&Wl[(((0 * 4 + t) * 2 + 0) * 64 + lane) * 8];
            short8 By1 = *(const short8*)&Wl[(((0 * 4 + t) * 2 + 1) * 64 + lane) * 8];
            short8 Bz0 = *(const short8*)&Wl[(((1 * 4 + t) * 2 + 0) * 64 + lane) * 8];
            short8 Bz1 = *(const short8*)&Wl[(((1 * 4 + t) * 2 + 1) * 64 + lane) * 8];

            f32x4 accY = {0.f, 0.f, 0.f, 0.f};
            accY = __builtin_amdgcn_mfma_f32_16x16x32_bf16(A[0], By0, accY, 0, 0, 0);
            accY = __builtin_amdgcn_mfma_f32_16x16x32_bf16(A[1], By1, accY, 0, 0, 0);
            f32x4 accZ = {0.f, 0.f, 0.f, 0.f};
            accZ = __builtin_amdgcn_mfma_f32_16x16x32_bf16(A[0], Bz0, accZ, 0, 0, 0);
            accZ = __builtin_amdgcn_mfma_f32_16x16x32_bf16(A[1], Bz1, accZ, 0, 0, 0);

            float bv = bias[t * 16 + n16];
#pragma unroll
            for (int r = 0; r < 4; ++r) {
                out[(size_t)(row0 + r) * D + t * 16 + n16] = accZ[r] + bv;
                unsigned int me = f2bf(accY[r]);
                unsigned int nb = (unsigned int)__shfl_xor((int)me, 1, 64) & 0xFFFFu;
                if ((lane & 1) == 0)
                    y_packed[((size_t)(row0 + r) * D + t * 16 + n16) >> 1] = me | (nb << 16);
            }
        }
    }
}

// ==================== half-bucket CSR build + gather ========================
// Block bb = (bucket b = bb>>1, half = bb&1). Reads the bucket's pairs
// coalesced (uint4, L2-hot), filters rows to its 128-node half, builds the
// half-CSR in LDS, then runs the proven register gather. 782 blocks x 8
// waves => ~3 blocks/CU (vs round-4's 1.5) for the latency-bound y gather.
__launch_bounds__(512, 4)
__global__ void csr_gather_kernel(const unsigned short* __restrict__ yu,
                                  const unsigned int* __restrict__ pairs,
                                  const int* __restrict__ bucket_cnt,
                                  float* __restrict__ out) {
    __shared__ int col_lds[HALF_PAD];     // 8 KB
    __shared__ int deg_s[128];
    __shared__ int start_s[128];
    __shared__ int lcur[128];
    __shared__ int cnt_s[128];
    __shared__ int wsum[2];

    int bb = blockIdx.x;
    int b = bb >> 1;
    int rbase = (bb & 1) << 7;            // 0 or 128
    int tid = threadIdx.x;
    int m = bucket_cnt[b];
    if (m > CAP) m = CAP;
    const uint4* pb4 = (const uint4*)(pairs + (size_t)b * CAP);  // 928 uint4

    if (tid < 128) cnt_s[tid] = 0;
    __syncthreads();

    // ---- load pairs coalesced: 928 uint4 over 512 threads (2/thread) ----
    uint4 pa = pb4[tid];
    uint4 pc = (tid < CAP / 4 - 512) ? pb4[tid + 512] : make_uint4(0u, 0u, 0u, 0u);
    int ea = 4 * tid, ec = 2048 + 4 * tid;
    bool a0 = ea + 0 < m, a1 = ea + 1 < m, a2 = ea + 2 < m, a3 = ea + 3 < m;
    bool c0 = ec + 0 < m, c1 = ec + 1 < m, c2 = ec + 2 < m, c3 = ec + 3 < m;

#define CNT(p, v) if (v) { int r = (int)((p) >> 17) - rbase; \
                           if ((unsigned)r < 128u) atomicAdd(&cnt_s[r], 1); }
    CNT(pa.x, a0) CNT(pa.y, a1) CNT(pa.z, a2) CNT(pa.w, a3)
    CNT(pc.x, c0) CNT(pc.y, c1) CNT(pc.z, c2) CNT(pc.w, c3)
#undef CNT
    __syncthreads();

    // ---- shuffle scan over 128 counts (waves 0..1) ----
    if (tid < 128) {
        int v = cnt_s[tid];
        int incl = v;
        for (int d = 1; d < 64; d <<= 1) {
            int t = __shfl_up(incl, d, 64);
            if ((tid & 63) >= d) incl += t;
        }
        if ((tid & 63) == 63) wsum[tid >> 6] = incl;
        deg_s[tid] = v;
        cnt_s[tid] = incl;
    }
    __syncthreads();
    if (tid < 128) {
        int pre = (tid >= 64) ? wsum[0] : 0;
        int excl = cnt_s[tid] + pre - deg_s[tid];
        start_s[tid] = excl;
        lcur[tid] = excl;
    }
    __syncthreads();

    // ---- scatter this half's cols into LDS ----
#define SCAT(p, v) if (v) { int r = (int)((p) >> 17) - rbase; \
                            if ((unsigned)r < 128u) { \
                                int c = (int)((p) & 0x1FFFFu); \
                                col_lds[atomicAdd(&lcur[r], 1) & (HALF_PAD - 1)] = \
                                    c < N_NODES ? c : 0; } }
    SCAT(pa.x, a0) SCAT(pa.y, a1) SCAT(pa.z, a2) SCAT(pa.w, a3)
    SCAT(pc.x, c0) SCAT(pc.y, c1) SCAT(pc.z, c2) SCAT(pc.w, c3)
#undef SCAT
    __syncthreads();

    // ---- proven 4-node/wave register gather (round-4 form) ----
    int wv = tid >> 6;                    // 0..7
    int lane = tid & 63;
    int s = lane >> 4;
    int q = lane & 15;

#pragma unroll 1
    for (int pk = 0; pk < 4; ++pk) {
        int n0 = wv * 16 + pk * 4;        // local node base, 0..124
        int nvx = deg_s[n0 + 0], nvy = deg_s[n0 + 1],
            nvz = deg_s[n0 + 2], nvw = deg_s[n0 + 3];
        int st0 = start_s[n0 + 0], st1 = start_s[n0 + 1],
            st2 = start_s[n0 + 2], st3 = start_s[n0 + 3];

        float4 a0v = make_float4(0.f, 0.f, 0.f, 0.f);
        float4 a1v = a0v, a2v = a0v, a3v = a0v;

        {
            int mm = nvx > nvy ? nvx : nvy;
            for (int j = 0; j < mm; j += 4) {
                int jj = j + s;
                int c0i = col_lds[(st0 + jj) & (HALF_PAD - 1)];
                int c1i = col_lds[(st1 + jj) & (HALF_PAD - 1)];
                c0i = (jj < nvx) ? c0i : 0;
                c1i = (jj < nvy) ? c1i : 0;
                ushort4 u0 = *(const ushort4*)&yu[(size_t)c0i * D + q * 4];
                ushort4 u1 = *(const ushort4*)&yu[(size_t)c1i * D + q * 4];
                if (jj < nvx) {
                    a0v.x += bf2f(u0.x); a0v.y += bf2f(u0.y);
                    a0v.z += bf2f(u0.z); a0v.w += bf2f(u0.w);
                }
                if (jj < nvy) {
                    a1v.x += bf2f(u1.x); a1v.y += bf2f(u1.y);
                    a1v.z += bf2f(u1.z); a1v.w += bf2f(u1.w);
                }
            }
        }
        {
            int mm = nvz > nvw ? nvz : nvw;
            for (int j = 0; j < mm; j += 4) {
                int jj = j + s;
                int c2i = col_lds[(st2 + jj) & (HALF_PAD - 1)];
                int c3i = col_lds[(st3 + jj) & (HALF_PAD - 1)];
                c2i = (jj < nvz) ? c2i : 0;
                c3i = (jj < nvw) ? c3i : 0;
                ushort4 u2 = *(const ushort4*)&yu[(size_t)c2i * D + q * 4];
                ushort4 u3 = *(const ushort4*)&yu[(size_t)c3i * D + q * 4];
                if (jj < nvz) {
                    a2v.x += bf2f(u2.x); a2v.y += bf2f(u2.y);
                    a2v.z += bf2f(u2.z); a2v.w += bf2f(u2.w);
                }
                if (jj < nvw) {
                    a3v.x += bf2f(u3.x); a3v.y += bf2f(u3.y);
                    a3v.z += bf2f(u3.z); a3v.w += bf2f(u3.w);
                }
            }
        }

#define BFLY(a) \
    a.x += __shfl_xor(a.x, 16, 64); a.y += __shfl_xor(a.y, 16, 64); \
    a.z += __shfl_xor(a.z, 16, 64); a.w += __shfl_xor(a.w, 16, 64); \
    a.x += __shfl_xor(a.x, 32, 64); a.y += __shfl_xor(a.y, 32, 64); \
    a.z += __shfl_xor(a.z, 32, 64); a.w += __shfl_xor(a.w, 32, 64);
        BFLY(a0v) BFLY(a1v) BFLY(a2v) BFLY(a3v)
#undef BFLY

        float inv0 = 1.0f / (float)(nvx > 1 ? nvx : 1);
        float inv1 = 1.0f / (float)(nvy > 1 ? nvy : 1);
        float inv2 = 1.0f / (float)(nvz > 1 ? nvz : 1);
        float inv3 = 1.0f / (float)(nvw > 1 ? nvw : 1);

        float4 rr = (s == 0) ? a0v : (s == 1) ? a1v : (s == 2) ? a2v : a3v;
        float invs = (s == 0) ? inv0 : (s == 1) ? inv1 : (s == 2) ? inv2 : inv3;
        int g = (b << BKT_SHIFT) + rbase + n0 + s;
        if (g < N_NODES) {
            size_t off = (size_t)g * D + q * 4;
            float4 z = *(const float4*)&out[off];
            z.x += rr.x * invs; z.y += rr.y * invs;
            z.z += rr.z * invs; z.w += rr.w * invs;
            *(float4*)&out[off] = z;
        }
    }
}

// ==================== tier-2: legacy CSR build + fused aggregate ============

__global__ void hist_kernel(const int4* __restrict__ row4, int* __restrict__ deg) {
    int t = blockIdx.x * blockDim.x + threadIdx.x;
    if (t < N_EDGES / 4) {
        int4 r = row4[t];
        atomicAdd(&deg[r.x], 1);
        atomicAdd(&deg[r.y], 1);
        atomicAdd(&deg[r.z], 1);
        atomicAdd(&deg[r.w], 1);
    }
}

__global__ void scan_block_kernel(const int* __restrict__ deg,
                                  int* __restrict__ cursor,
                                  int* __restrict__ bsum) {
    __shared__ int s[256];
    int tid = threadIdx.x;
    int gid = blockIdx.x * 256 + tid;
    int v = (gid < N_NODES) ? deg[gid] : 0;
    s[tid] = v;
    __syncthreads();
    for (int d = 1; d < 256; d <<= 1) {
        int t = (tid >= d) ? s[tid - d] : 0;
        __syncthreads();
        s[tid] += t;
        __syncthreads();
    }
    if (gid < N_NODES) cursor[gid] = s[tid] - v;
    if (tid == 255) bsum[blockIdx.x] = s[255];
}

__global__ void add_offsets_kernel(int* __restrict__ cursor,
                                   const int* __restrict__ bsum_raw) {
    __shared__ int red[256];
    int tid = threadIdx.x;
    int b = blockIdx.x;
    int sum = 0;
    for (int i = tid; i < b; i += 256) sum += bsum_raw[i];
    red[tid] = sum;
    __syncthreads();
    for (int off = 128; off > 0; off >>= 1) {
        if (tid < off) red[tid] += red[tid + off];
        __syncthreads();
    }
    int gid = b * 256 + tid;
    if (gid < N_NODES) cursor[gid] += red[0];
}

__global__ void scatter_build_kernel(const int4* __restrict__ row4,
                                     const int4* __restrict__ col4,
                                     int* __restrict__ cursor,
                                     int* __restrict__ col_sorted) {
    int t = blockIdx.x * blockDim.x + threadIdx.x;
    if (t < N_EDGES / 4) {
        int4 r = row4[t];
        int4 c = col4[t];
        col_sorted[atomicAdd(&cursor[r.x], 1)] = c.x;
        col_sorted[atomicAdd(&cursor[r.y], 1)] = c.y;
        col_sorted[atomicAdd(&cursor[r.z], 1)] = c.z;
        col_sorted[atomicAdd(&cursor[r.w], 1)] = c.w;
    }
}

__launch_bounds__(512, 8)
__global__ void aggregate_kernel(const float* __restrict__ x,
                                 const int* __restrict__ cursor_end,
                                 const int* __restrict__ deg,
                                 const int* __restrict__ col_sorted,
                                 const float* __restrict__ W,
                                 const float* __restrict__ Wr,
                                 const float* __restrict__ bias,
                                 float* __restrict__ out) {
    __shared__ float Ws[D * D];
    __shared__ float Wrs[D * D];
    __shared__ float agg_s[8][D];
    __shared__ float x_s[8][D];

    for (int i = threadIdx.x; i < D * D / 4; i += 512) {
        ((float4*)Ws)[i]  = ((const float4*)W)[i];
        ((float4*)Wrs)[i] = ((const float4*)Wr)[i];
    }
    __syncthreads();

    int wv = threadIdx.x >> 6;
    int lane = threadIdx.x & 63;
    int s = lane >> 4;
    int q = lane & 15;
    float bf = bias[lane];

    int node0 = (blockIdx.x * 8 + wv) * 4;

#pragma unroll 1
    for (int nn = 0; nn < 4; ++nn) {
        int r = node0 + nn;
        int n = deg[r];
        int start = cursor_end[r] - n;

        float4 acc = make_float4(0.f, 0.f, 0.f, 0.f);
        for (int base = 0; base < n; base += 64) {
            int m = n - base; if (m > 64) m = 64;
            int idx = 0;
            if (lane < m) idx = col_sorted[start + base + lane];
            for (int j = 0; j < m; j += 4) {
                int jj = j + s;
                int c = __shfl(idx, jj, 64);
                if (jj < m) {
                    float4 v = *(const float4*)&x[(size_t)c * D + q * 4];
                    acc.x += v.x; acc.y += v.y; acc.z += v.z; acc.w += v.w;
                }
            }
        }
        acc.x += __shfl_xor(acc.x, 16, 64);
        acc.y += __shfl_xor(acc.y, 16, 64);
        acc.z += __shfl_xor(acc.z, 16, 64);
        acc.w += __shfl_xor(acc.w, 16, 64);
        acc.x += __shfl_xor(acc.x, 32, 64);
        acc.y += __shfl_xor(acc.y, 32, 64);
        acc.z += __shfl_xor(acc.z, 32, 64);
        acc.w += __shfl_xor(acc.w, 32, 64);

        float inv = 1.0f / (float)(n > 1 ? n : 1);
        if (lane < 16) {
            float4 a = make_float4(acc.x * inv, acc.y * inv, acc.z * inv, acc.w * inv);
            *(float4*)&agg_s[wv][q * 4] = a;
            *(float4*)&x_s[wv][q * 4] = *(const float4*)&x[(size_t)r * D + q * 4];
        }
        __builtin_amdgcn_wave_barrier();

        int f = lane;
        float o = bf;
        const float4* av = (const float4*)agg_s[wv];
        const float4* xv = (const float4*)x_s[wv];
#pragma unroll
        for (int k4 = 0; k4 < 16; ++k4) {
            float4 a = av[k4];
            float4 xx = xv[k4];
            int k = k4 * 4;
            o += a.x * Ws[(k + 0) * D + f] + xx.x * Wrs[(k + 0) * D + f];
            o += a.y * Ws[(k + 1) * D + f] + xx.y * Wrs[(k + 1) * D + f];
            o += a.z * Ws[(k + 2) * D + f] + xx.z * Wrs[(k + 2) * D + f];
            o += a.w * Ws[(k + 3) * D + f] + xx.w * Wrs[(k + 3) * D + f];
        }
        out[(size_t)r * D + f] = o;
        __builtin_amdgcn_wave_barrier();
    }
}

// ==================== tier-3: atomic fallback (400 KB ws) ====================

__global__ void zero_kernel(float* __restrict__ summed, float* __restrict__ cnt) {
    int stride = gridDim.x * blockDim.x;
    int i = blockIdx.x * blockDim.x + threadIdx.x;
    const int total = N_NODES * D;
    for (int idx = i; idx < total; idx += stride) summed[idx] = 0.0f;
    for (int idx = i; idx < N_NODES; idx += stride) cnt[idx] = 0.0f;
}

__global__ void scatter_atomic_kernel(const float* __restrict__ x,
                                      const int* __restrict__ row,
                                      const int* __restrict__ col,
                                      float* __restrict__ summed,
                                      float* __restrict__ cnt) {
    long long gid = (long long)blockIdx.x * blockDim.x + threadIdx.x;
    const long long total = (long long)N_EDGES * D;
    if (gid >= total) return;
    int e = (int)(gid >> 6);
    int f = (int)(gid & 63);
    int r = row[e];
    int c = col[e];
    atomicAdd(&summed[r * D + f], x[c * D + f]);
    if (f == 0) atomicAdd(&cnt[r], 1.0f);
}

__global__ void finish_kernel(const float* __restrict__ x,
                              const float* __restrict__ W,
                              const float* __restrict__ Wr,
                              const float* __restrict__ bias,
                              const float* __restrict__ cnt,
                              float* __restrict__ out) {
    __shared__ float agg_s[4][D];
    __shared__ float x_s[4][D];
    int lrow = threadIdx.x >> 6;
    int f = threadIdx.x & 63;
    int r = blockIdx.x * 4 + lrow;

    float c = cnt[r];
    float inv = 1.0f / fmaxf(c, 1.0f);
    agg_s[lrow][f] = out[r * D + f] * inv;
    x_s[lrow][f] = x[r * D + f];
    __syncthreads();

    float acc = bias[f];
#pragma unroll 8
    for (int k = 0; k < D; ++k) {
        acc += agg_s[lrow][k] * W[k * D + f];
        acc += x_s[lrow][k] * Wr[k * D + f];
    }
    out[r * D + f] = acc;
}

// ==================== launch ====================

extern "C" void kernel_launch(void* const* d_in, const int* in_sizes, int n_in,
                              void* d_out, int out_size, void* d_ws, size_t ws_size,
                              hipStream_t stream) {
    const float* x    = (const float*)d_in[0];
    const int*   ei   = (const int*)d_in[1];   // [2, E]: row = ei, col = ei + E
    const float* W    = (const float*)d_in[2];
    const float* Wr   = (const float*)d_in[3];
    const float* bias = (const float*)d_in[4];
    float* out = (float*)d_out;

    const int* row = ei;
    const int* col = ei + N_EDGES;

    // tier-1 layout: bucket_cnt(2048) | pairs(391*3712*4 = 5,805,568) | y(12.8M)
    const size_t t1_cnt   = 0;
    const size_t t1_pairs = 2048;
    const size_t t1_y     = 2048 + (size_t)NBKT * CAP * 4;         //  5,807,616
    const size_t t1_need  = t1_y + (size_t)N_NODES * D * 2;        // 18,607,616

    const size_t csr_bytes = (size_t)2 * N_NODES * 4 + 2048 + (size_t)N_EDGES * 4;

    if (ws_size >= t1_need) {
        char* ws = (char*)d_ws;
        int* bcnt = (int*)(ws + t1_cnt);
        unsigned int* pairs    = (unsigned int*)(ws + t1_pairs);
        unsigned int* y_packed = (unsigned int*)(ws + t1_y);

        zero_bcnt_kernel<<<1, 512, 0, stream>>>(bcnt);
        bin_pre_kernel<<<BIN_BLOCKS + PRE_BLOCKS, 512, 0, stream>>>(
            row, col, bcnt, pairs, x, W, Wr, bias, y_packed, out);
        csr_gather_kernel<<<HBKT, 512, 0, stream>>>(
            (const unsigned short*)y_packed, pairs, bcnt, out);
    } else if (ws_size >= csr_bytes) {
        char* ws = (char*)d_ws;
        int* deg        = (int*)(ws);
        int* cursor     = (int*)(ws + (size_t)1 * N_NODES * 4);
        int* bsum       = (int*)(ws + (size_t)2 * N_NODES * 4);
        int* col_sorted = (int*)(ws + (size_t)2 * N_NODES * 4 + 2048);

        hipMemsetAsync(deg, 0, (size_t)N_NODES * 4, stream);
        hist_kernel<<<(N_EDGES / 4 + 255) / 256, 256, 0, stream>>>((const int4*)row, deg);
        scan_block_kernel<<<NB, 256, 0, stream>>>(deg, cursor, bsum);
        add_offsets_kernel<<<NB, 256, 0, stream>>>(cursor, bsum);
        scatter_build_kernel<<<(N_EDGES / 4 + 255) / 256, 256, 0, stream>>>(
            (const int4*)row, (const int4*)col, cursor, col_sorted);
        aggregate_kernel<<<N_NODES / 32, 512, 0, stream>>>(x, cursor, deg, col_sorted, W, Wr, bias, out);
    } else {
        float* cnt = (float*)d_ws;   // N_NODES floats
        zero_kernel<<<4096, 256, 0, stream>>>(out, cnt);
        long long total = (long long)N_EDGES * D;
        int blocks = (int)((total + 255) / 256);
        scatter_atomic_kernel<<<blocks, 256, 0, stream>>>(x, row, col, out, cnt);
        finish_kernel<<<(N_NODES + 3) / 4, 256, 0, stream>>>(x, W, Wr, bias, cnt, out);
    }
}